// Round 1
// baseline (197.571 us; speedup 1.0000x reference)
//
#include <hip/hip_runtime.h>

// Problem sizes (fixed by the reference)
#define BDIM 8
#define QDIM 1024
#define KDIM 1024
#define HDIM 64   // = DQ = DK = DV

constexpr float kLog2e = 1.4426950408889634f;

// fast tanh: tanh(x) = (t-1)/(t+1), t = 2^(2*log2e*x); clamp keeps exp2 finite.
__device__ __forceinline__ float tanh_fast(float x) {
  float xc = __builtin_amdgcn_fmed3f(x, -30.0f, 30.0f);
  float t  = __builtin_amdgcn_exp2f(xc * (2.0f * kLog2e));
  return (t - 1.0f) * __builtin_amdgcn_rcpf(t + 1.0f);
}

// ---------------------------------------------------------------------------
// K1/K2: Y[r][h] = sum_d X[r][d] * W[d][h]   (D = H = 64)
// block = 256 threads, handles 64 consecutive rows.
// ---------------------------------------------------------------------------
__global__ __launch_bounds__(256) void proj64(const float* __restrict__ X,
                                              const float* __restrict__ W,
                                              float* __restrict__ Y) {
  __shared__ __align__(16) float xs[64][68];  // +4 pad: 16B-aligned rows, no bank alias
  __shared__ __align__(16) float ws[64][64];
  const int t = threadIdx.x;
  const long long base = (long long)blockIdx.x * 64 * 64;

  {
    const int r = t >> 4, sl = t & 15;
#pragma unroll
    for (int i = 0; i < 4; ++i) {
      *(float4*)&xs[r + i * 16][sl * 4] =
          *(const float4*)&X[base + (long long)(r + i * 16) * 64 + sl * 4];
      *(float4*)&ws[r + i * 16][sl * 4] =
          *(const float4*)&W[(r + i * 16) * 64 + sl * 4];
    }
  }
  __syncthreads();

  const int r = t >> 2;            // 0..63
  const int c0 = (t & 3) * 16;     // 0,16,32,48
  float acc[16];
#pragma unroll
  for (int j = 0; j < 16; ++j) acc[j] = 0.0f;

#pragma unroll 8
  for (int d = 0; d < 64; ++d) {
    const float xv = xs[r][d];
#pragma unroll
    for (int j4 = 0; j4 < 4; ++j4) {
      float4 w4 = *(float4*)&ws[d][c0 + j4 * 4];
      acc[j4 * 4 + 0] = fmaf(xv, w4.x, acc[j4 * 4 + 0]);
      acc[j4 * 4 + 1] = fmaf(xv, w4.y, acc[j4 * 4 + 1]);
      acc[j4 * 4 + 2] = fmaf(xv, w4.z, acc[j4 * 4 + 2]);
      acc[j4 * 4 + 3] = fmaf(xv, w4.w, acc[j4 * 4 + 3]);
    }
  }
#pragma unroll
  for (int j4 = 0; j4 < 4; ++j4) {
    float4 o = make_float4(acc[j4 * 4 + 0], acc[j4 * 4 + 1],
                           acc[j4 * 4 + 2], acc[j4 * 4 + 3]);
    *(float4*)&Y[base + (long long)r * 64 + c0 + j4 * 4] = o;
  }
}

// ---------------------------------------------------------------------------
// K3: scores[b,q,k] = sum_h wv[h] * tanh(qh[b,q,h] + kh[b,k,h])
// block = 256 threads: 16 q-rows x 64 k-cols tile. Thread (q = t>>4, kg = t&15)
// computes 4 scores (k = kg*4 + j). k-tile is XOR-swizzled in LDS so the
// stride-256B row reads are 2-way (free) instead of 16-way bank conflicts.
// ---------------------------------------------------------------------------
__global__ __launch_bounds__(256) void scores_kernel(
    const float* __restrict__ qh, const float* __restrict__ kh,
    const float* __restrict__ wv, const int* __restrict__ vlens,
    float* __restrict__ scores) {
  const int b = blockIdx.z;
  const int q0 = blockIdx.y * 16;
  const int k0 = blockIdx.x * 64;
  const int vlen = vlens[b];
  if (k0 >= vlen) return;  // fully masked tile: softmax ignores it

  __shared__ __align__(16) float qs[16][64];
  __shared__ __align__(16) float ks[64][64];
  __shared__ __align__(16) float wvs[64];
  const int t = threadIdx.x;

  if (t < 16) *(float4*)&wvs[t * 4] = *(const float4*)&wv[t * 4];
  {
    const int r = t >> 4, sl = t & 15;
    *(float4*)&qs[r][sl * 4] =
        *(const float4*)&qh[(long long)(b * QDIM + q0 + r) * 64 + sl * 4];
  }
#pragma unroll
  for (int i = 0; i < 4; ++i) {
    const int f = i * 256 + t;
    const int k = f >> 4, sl = f & 15;
    const int key = (k ^ (k >> 2)) & 15;
    *(float4*)&ks[k][(sl ^ key) * 4] =
        *(const float4*)&kh[(long long)(b * KDIM + k0 + k) * 64 + sl * 4];
  }
  __syncthreads();

  const int q = t >> 4, kg = t & 15;
  float acc[4] = {0.0f, 0.0f, 0.0f, 0.0f};

#pragma unroll 4
  for (int h4 = 0; h4 < 16; ++h4) {
    const float4 q4 = *(float4*)&qs[q][h4 * 4];
    const float4 w4 = *(float4*)&wvs[h4 * 4];
#pragma unroll
    for (int j = 0; j < 4; ++j) {
      const int k = kg * 4 + j;
      const int key = (k ^ (k >> 2)) & 15;
      const float4 k4 = *(float4*)&ks[k][(h4 ^ key) * 4];
      acc[j] += w4.x * tanh_fast(q4.x + k4.x);
      acc[j] += w4.y * tanh_fast(q4.y + k4.y);
      acc[j] += w4.z * tanh_fast(q4.z + k4.z);
      acc[j] += w4.w * tanh_fast(q4.w + k4.w);
    }
  }
  float4 o = make_float4(acc[0], acc[1], acc[2], acc[3]);
  *(float4*)&scores[(long long)(b * QDIM + q0 + q) * KDIM + k0 + kg * 4] = o;
}

// ---------------------------------------------------------------------------
// K4: masked row softmax, in place. block = 256 threads = 4 rows x 64 lanes.
// Masked positions -> -3e38 -> exp2 underflows to exact 0 (matches NEG=-1e6
// reference semantics in fp32).
// ---------------------------------------------------------------------------
__global__ __launch_bounds__(256) void softmax_kernel(
    float* __restrict__ scores, const int* __restrict__ vlens) {
  const int t = threadIdx.x;
  const int row = blockIdx.x * 4 + (t >> 6);
  const int b = row >> 10;  // QDIM = 1024
  const int lane = t & 63;
  const int vlen = vlens[b];
  float* srow = scores + (long long)row * KDIM;

  float4 v[4];
  float m = -3.0e38f;
#pragma unroll
  for (int i = 0; i < 4; ++i) {
    const int k = i * 256 + lane * 4;
    v[i] = *(const float4*)&srow[k];
    v[i].x = (k + 0 < vlen) ? v[i].x : -3.0e38f;
    v[i].y = (k + 1 < vlen) ? v[i].y : -3.0e38f;
    v[i].z = (k + 2 < vlen) ? v[i].z : -3.0e38f;
    v[i].w = (k + 3 < vlen) ? v[i].w : -3.0e38f;
    m = fmaxf(m, fmaxf(fmaxf(v[i].x, v[i].y), fmaxf(v[i].z, v[i].w)));
  }
#pragma unroll
  for (int s = 1; s < 64; s <<= 1) m = fmaxf(m, __shfl_xor(m, s, 64));

  float4 e[4];
  float sum = 0.0f;
#pragma unroll
  for (int i = 0; i < 4; ++i) {
    e[i].x = __builtin_amdgcn_exp2f((v[i].x - m) * kLog2e);
    e[i].y = __builtin_amdgcn_exp2f((v[i].y - m) * kLog2e);
    e[i].z = __builtin_amdgcn_exp2f((v[i].z - m) * kLog2e);
    e[i].w = __builtin_amdgcn_exp2f((v[i].w - m) * kLog2e);
    sum += (e[i].x + e[i].y) + (e[i].z + e[i].w);
  }
#pragma unroll
  for (int s = 1; s < 64; s <<= 1) sum += __shfl_xor(sum, s, 64);
  const float inv = __builtin_amdgcn_rcpf(sum);

#pragma unroll
  for (int i = 0; i < 4; ++i) {
    const int k = i * 256 + lane * 4;
    float4 o = make_float4(e[i].x * inv, e[i].y * inv, e[i].z * inv, e[i].w * inv);
    *(float4*)&srow[k] = o;
  }
}

// ---------------------------------------------------------------------------
// K5: out[b,q,d] = sum_k attn[b,q,k] * V[b,k,d]. block = 256 threads,
// 32 q-rows per block, k tiled by 64. Thread owns 2 q-rows x 4 d.
// Only k-tiles below valid_len contribute (attn is exactly 0 past vlen).
// ---------------------------------------------------------------------------
__global__ __launch_bounds__(256) void pv_kernel(
    const float* __restrict__ attn, const float* __restrict__ V,
    const int* __restrict__ vlens, float* __restrict__ out) {
  const int b = blockIdx.y;
  const int q0 = blockIdx.x * 32;
  const int vlen = vlens[b];
  const int ntiles = (vlen + 63) >> 6;

  __shared__ __align__(16) float as[32][68];  // +4 pad: q-row reads spread banks
  __shared__ __align__(16) float vs[64][64];
  const int t = threadIdx.x;
  const int qp = t >> 4;           // 0..15 -> rows qp and qp+16
  const int dsl = (t & 15) * 4;    // d slice

  float4 a0 = make_float4(0, 0, 0, 0);
  float4 a1 = make_float4(0, 0, 0, 0);

  for (int kt = 0; kt < ntiles; ++kt) {
    __syncthreads();
#pragma unroll
    for (int i = 0; i < 2; ++i) {
      const int f = i * 256 + t;
      const int r = f >> 4, sl = f & 15;
      *(float4*)&as[r][sl * 4] =
          *(const float4*)&attn[(long long)(b * QDIM + q0 + r) * KDIM + kt * 64 + sl * 4];
    }
#pragma unroll
    for (int i = 0; i < 4; ++i) {
      const int f = i * 256 + t;
      const int k = f >> 4, sl = f & 15;
      *(float4*)&vs[k][sl * 4] =
          *(const float4*)&V[(long long)(b * KDIM + kt * 64 + k) * 64 + sl * 4];
    }
    __syncthreads();

#pragma unroll 4
    for (int k4 = 0; k4 < 16; ++k4) {
      const float4 aq0 = *(float4*)&as[qp][k4 * 4];
      const float4 aq1 = *(float4*)&as[qp + 16][k4 * 4];
      const float aw0[4] = {aq0.x, aq0.y, aq0.z, aq0.w};
      const float aw1[4] = {aq1.x, aq1.y, aq1.z, aq1.w};
#pragma unroll
      for (int e = 0; e < 4; ++e) {
        const float4 vv = *(float4*)&vs[k4 * 4 + e][dsl];
        a0.x = fmaf(aw0[e], vv.x, a0.x);
        a0.y = fmaf(aw0[e], vv.y, a0.y);
        a0.z = fmaf(aw0[e], vv.z, a0.z);
        a0.w = fmaf(aw0[e], vv.w, a0.w);
        a1.x = fmaf(aw1[e], vv.x, a1.x);
        a1.y = fmaf(aw1[e], vv.y, a1.y);
        a1.z = fmaf(aw1[e], vv.z, a1.z);
        a1.w = fmaf(aw1[e], vv.w, a1.w);
      }
    }
  }
  *(float4*)&out[(long long)(b * QDIM + q0 + qp) * 64 + dsl] = a0;
  *(float4*)&out[(long long)(b * QDIM + q0 + qp + 16) * 64 + dsl] = a1;
}

// ---------------------------------------------------------------------------
extern "C" void kernel_launch(void* const* d_in, const int* in_sizes, int n_in,
                              void* d_out, int out_size, void* d_ws, size_t ws_size,
                              hipStream_t stream) {
  const float* queries = (const float*)d_in[0];
  const float* keys    = (const float*)d_in[1];
  const float* values  = (const float*)d_in[2];
  const int*   vlens   = (const int*)d_in[3];
  const float* Wq      = (const float*)d_in[4];
  const float* Wk      = (const float*)d_in[5];
  const float* wv      = (const float*)d_in[6];
  float* out = (float*)d_out;

  float* qh     = (float*)d_ws;                       // B*Q*H  = 2 MB
  float* kh     = qh + (size_t)BDIM * QDIM * HDIM;    // B*K*H  = 2 MB
  float* scores = kh + (size_t)BDIM * KDIM * HDIM;    // B*Q*K  = 32 MB

  proj64<<<dim3(BDIM * QDIM / 64), 256, 0, stream>>>(queries, Wq, qh);
  proj64<<<dim3(BDIM * KDIM / 64), 256, 0, stream>>>(keys, Wk, kh);
  scores_kernel<<<dim3(KDIM / 64, QDIM / 16, BDIM), 256, 0, stream>>>(
      qh, kh, wv, vlens, scores);
  softmax_kernel<<<dim3(BDIM * QDIM / 4), 256, 0, stream>>>(scores, vlens);
  pv_kernel<<<dim3(QDIM / 32, BDIM), 256, 0, stream>>>(scores, values, vlens, out);
}

// Round 2
// 147.996 us; speedup vs baseline: 1.3350x; 1.3350x over previous
//
#include <hip/hip_runtime.h>

// Problem sizes (fixed by the reference)
#define BDIM 8
#define QDIM 1024
#define KDIM 1024
#define HDIM 64   // = DQ = DK = DV

constexpr float kLog2e = 1.4426950408889634f;
constexpr float kC2 = 2.0f * kLog2e;  // folded into projections: q' = c*q_hat

// ---------------------------------------------------------------------------
// K1: both projections in one launch. blocks 0..127 -> queries*Wq -> qh,
// blocks 128..255 -> keys*Wk -> kh. Output is scaled by kC2 so the score
// kernel's exp2 argument is just q'+k'.
// ---------------------------------------------------------------------------
__global__ __launch_bounds__(256) void proj_both(
    const float* __restrict__ queries, const float* __restrict__ keys,
    const float* __restrict__ Wq, const float* __restrict__ Wk,
    float* __restrict__ qh, float* __restrict__ kh) {
  const int bid = blockIdx.x;
  const bool isK = bid >= 128;
  const float* X = isK ? keys : queries;
  const float* W = isK ? Wk : Wq;
  float* Y = isK ? kh : qh;
  const long long base = (long long)(bid & 127) * 64 * 64;

  __shared__ __align__(16) float xs[64][68];
  __shared__ __align__(16) float ws[64][64];
  const int t = threadIdx.x;
  {
    const int r = t >> 4, sl = t & 15;
#pragma unroll
    for (int i = 0; i < 4; ++i) {
      *(float4*)&xs[r + i * 16][sl * 4] =
          *(const float4*)&X[base + (long long)(r + i * 16) * 64 + sl * 4];
      *(float4*)&ws[r + i * 16][sl * 4] =
          *(const float4*)&W[(r + i * 16) * 64 + sl * 4];
    }
  }
  __syncthreads();

  const int r = t >> 2;
  const int c0 = (t & 3) * 16;
  float acc[16];
#pragma unroll
  for (int j = 0; j < 16; ++j) acc[j] = 0.0f;

#pragma unroll 8
  for (int d = 0; d < 64; ++d) {
    const float xv = xs[r][d];
#pragma unroll
    for (int j4 = 0; j4 < 4; ++j4) {
      float4 w4 = *(float4*)&ws[d][c0 + j4 * 4];
      acc[j4 * 4 + 0] = fmaf(xv, w4.x, acc[j4 * 4 + 0]);
      acc[j4 * 4 + 1] = fmaf(xv, w4.y, acc[j4 * 4 + 1]);
      acc[j4 * 4 + 2] = fmaf(xv, w4.z, acc[j4 * 4 + 2]);
      acc[j4 * 4 + 3] = fmaf(xv, w4.w, acc[j4 * 4 + 3]);
    }
  }
#pragma unroll
  for (int j4 = 0; j4 < 4; ++j4) {
    float4 o = make_float4(acc[j4 * 4 + 0] * kC2, acc[j4 * 4 + 1] * kC2,
                           acc[j4 * 4 + 2] * kC2, acc[j4 * 4 + 3] * kC2);
    *(float4*)&Y[base + (long long)r * 64 + c0 + j4 * 4] = o;
  }
}

// ---------------------------------------------------------------------------
// K2: scores[b,q,k] = sum_h wv[h]*tanh(qhat+khat)
//   = sumw - 2*sum_h wv[h]*rcp(1 + exp2(q'+k'))      (q',k' pre-scaled)
// block = 256 threads: 32 q-rows x 64 k tile. Thread (q=t>>3, kg=t&7) owns
// 8 consecutive k (kg*8..kg*8+7): 32 independent 5-op chains per h4 step.
// k-tile swizzled with key=(k^(k>>3))&15: conflict-free for stride-8 k reads.
// wv[] is read via uniform scalar loads (SGPR operand, free in the fma).
// ---------------------------------------------------------------------------
__global__ __launch_bounds__(256) void scores_kernel(
    const float* __restrict__ qh, const float* __restrict__ kh,
    const float* __restrict__ wv, const int* __restrict__ vlens,
    float* __restrict__ scores) {
  const int b = blockIdx.z;
  const int q0 = blockIdx.y * 32;
  const int k0 = blockIdx.x * 64;
  const int vlen = vlens[b];
  if (k0 >= vlen) return;  // fully masked tile: softmax ignores it

  __shared__ __align__(16) float qs[32][68];  // +4 pad: q-row reads conflict-free
  __shared__ __align__(16) float ks[64][64];  // XOR-swizzled
  const int t = threadIdx.x;

  {
    const int r = t >> 4, sl = t & 15;
#pragma unroll
    for (int i = 0; i < 2; ++i)
      *(float4*)&qs[r + i * 16][sl * 4] =
          *(const float4*)&qh[(long long)(b * QDIM + q0 + r + i * 16) * 64 + sl * 4];
  }
#pragma unroll
  for (int i = 0; i < 4; ++i) {
    const int f = i * 256 + t;
    const int k = f >> 4, sl = f & 15;
    const int key = (k ^ (k >> 3)) & 15;
    *(float4*)&ks[k][(sl ^ key) * 4] =
        *(const float4*)&kh[(long long)(b * KDIM + k0 + k) * 64 + sl * 4];
  }
  float sumw = 0.0f;
#pragma unroll
  for (int h = 0; h < 64; ++h) sumw += wv[h];  // uniform -> scalar loads
  __syncthreads();

  const int q = t >> 3;        // 0..31
  const int kbase = (t & 7) * 8;

  float acc[8];
#pragma unroll
  for (int j = 0; j < 8; ++j) acc[j] = 0.0f;
  int keyj[8];
#pragma unroll
  for (int j = 0; j < 8; ++j) {
    const int k = kbase + j;
    keyj[j] = (k ^ (k >> 3)) & 15;
  }

#pragma unroll
  for (int h4 = 0; h4 < 16; ++h4) {
    const float4 q4 = *(float4*)&qs[q][h4 * 4];
    const float w0 = wv[h4 * 4 + 0], w1 = wv[h4 * 4 + 1];
    const float w2 = wv[h4 * 4 + 2], w3 = wv[h4 * 4 + 3];
#pragma unroll
    for (int j = 0; j < 8; ++j) {
      const float4 k4 = *(float4*)&ks[kbase + j][((h4 ^ keyj[j]) & 15) * 4];
      const float r0 = __builtin_amdgcn_rcpf(__builtin_amdgcn_exp2f(q4.x + k4.x) + 1.0f);
      const float r1 = __builtin_amdgcn_rcpf(__builtin_amdgcn_exp2f(q4.y + k4.y) + 1.0f);
      const float r2 = __builtin_amdgcn_rcpf(__builtin_amdgcn_exp2f(q4.z + k4.z) + 1.0f);
      const float r3 = __builtin_amdgcn_rcpf(__builtin_amdgcn_exp2f(q4.w + k4.w) + 1.0f);
      acc[j] = fmaf(w0, r0, acc[j]);
      acc[j] = fmaf(w1, r1, acc[j]);
      acc[j] = fmaf(w2, r2, acc[j]);
      acc[j] = fmaf(w3, r3, acc[j]);
    }
  }

  float sc[8];
#pragma unroll
  for (int j = 0; j < 8; ++j) sc[j] = fmaf(-2.0f, acc[j], sumw);
  float* srow = &scores[(long long)(b * QDIM + q0 + q) * KDIM + k0 + kbase];
  *(float4*)&srow[0] = make_float4(sc[0], sc[1], sc[2], sc[3]);
  *(float4*)&srow[4] = make_float4(sc[4], sc[5], sc[6], sc[7]);
}

// ---------------------------------------------------------------------------
// K3: masked row softmax, in place. block = 256 threads = 4 rows x 64 lanes.
// ---------------------------------------------------------------------------
__global__ __launch_bounds__(256) void softmax_kernel(
    float* __restrict__ scores, const int* __restrict__ vlens) {
  const int t = threadIdx.x;
  const int row = blockIdx.x * 4 + (t >> 6);
  const int b = row >> 10;  // QDIM = 1024
  const int lane = t & 63;
  const int vlen = vlens[b];
  float* srow = scores + (long long)row * KDIM;

  float4 v[4];
  float m = -3.0e38f;
#pragma unroll
  for (int i = 0; i < 4; ++i) {
    const int k = i * 256 + lane * 4;
    v[i] = *(const float4*)&srow[k];
    v[i].x = (k + 0 < vlen) ? v[i].x : -3.0e38f;
    v[i].y = (k + 1 < vlen) ? v[i].y : -3.0e38f;
    v[i].z = (k + 2 < vlen) ? v[i].z : -3.0e38f;
    v[i].w = (k + 3 < vlen) ? v[i].w : -3.0e38f;
    m = fmaxf(m, fmaxf(fmaxf(v[i].x, v[i].y), fmaxf(v[i].z, v[i].w)));
  }
#pragma unroll
  for (int s = 1; s < 64; s <<= 1) m = fmaxf(m, __shfl_xor(m, s, 64));

  float4 e[4];
  float sum = 0.0f;
#pragma unroll
  for (int i = 0; i < 4; ++i) {
    e[i].x = __builtin_amdgcn_exp2f((v[i].x - m) * kLog2e);
    e[i].y = __builtin_amdgcn_exp2f((v[i].y - m) * kLog2e);
    e[i].z = __builtin_amdgcn_exp2f((v[i].z - m) * kLog2e);
    e[i].w = __builtin_amdgcn_exp2f((v[i].w - m) * kLog2e);
    sum += (e[i].x + e[i].y) + (e[i].z + e[i].w);
  }
#pragma unroll
  for (int s = 1; s < 64; s <<= 1) sum += __shfl_xor(sum, s, 64);
  const float inv = __builtin_amdgcn_rcpf(sum);

#pragma unroll
  for (int i = 0; i < 4; ++i) {
    const int k = i * 256 + lane * 4;
    float4 o = make_float4(e[i].x * inv, e[i].y * inv, e[i].z * inv, e[i].w * inv);
    *(float4*)&srow[k] = o;
  }
}

// ---------------------------------------------------------------------------
// K4: out[b,q,d] = sum_k attn[b,q,k]*V[b,k,d]. 16 q-rows per block (512
// blocks -> 2/CU), k tiled by 64. Thread owns 1 q-row x 4 d.
// ---------------------------------------------------------------------------
__global__ __launch_bounds__(256) void pv_kernel(
    const float* __restrict__ attn, const float* __restrict__ V,
    const int* __restrict__ vlens, float* __restrict__ out) {
  const int b = blockIdx.y;
  const int q0 = blockIdx.x * 16;
  const int vlen = vlens[b];
  const int ntiles = (vlen + 63) >> 6;

  __shared__ __align__(16) float as[16][68];
  __shared__ __align__(16) float vs[64][64];
  const int t = threadIdx.x;
  const int qp = t >> 4;           // 0..15
  const int dsl = (t & 15) * 4;

  float4 a0 = make_float4(0, 0, 0, 0);

  for (int kt = 0; kt < ntiles; ++kt) {
    __syncthreads();
    {
      const int r = t >> 4, sl = t & 15;
      *(float4*)&as[r][sl * 4] =
          *(const float4*)&attn[(long long)(b * QDIM + q0 + r) * KDIM + kt * 64 + sl * 4];
    }
#pragma unroll
    for (int i = 0; i < 4; ++i) {
      const int f = i * 256 + t;
      const int k = f >> 4, sl = f & 15;
      *(float4*)&vs[k][sl * 4] =
          *(const float4*)&V[(long long)(b * KDIM + kt * 64 + k) * 64 + sl * 4];
    }
    __syncthreads();

#pragma unroll 4
    for (int k4 = 0; k4 < 16; ++k4) {
      const float4 a4 = *(float4*)&as[qp][k4 * 4];
      const float aw[4] = {a4.x, a4.y, a4.z, a4.w};
#pragma unroll
      for (int e = 0; e < 4; ++e) {
        const float4 vv = *(float4*)&vs[k4 * 4 + e][dsl];
        a0.x = fmaf(aw[e], vv.x, a0.x);
        a0.y = fmaf(aw[e], vv.y, a0.y);
        a0.z = fmaf(aw[e], vv.z, a0.z);
        a0.w = fmaf(aw[e], vv.w, a0.w);
      }
    }
  }
  *(float4*)&out[(long long)(b * QDIM + q0 + qp) * 64 + dsl] = a0;
}

// ---------------------------------------------------------------------------
extern "C" void kernel_launch(void* const* d_in, const int* in_sizes, int n_in,
                              void* d_out, int out_size, void* d_ws, size_t ws_size,
                              hipStream_t stream) {
  const float* queries = (const float*)d_in[0];
  const float* keys    = (const float*)d_in[1];
  const float* values  = (const float*)d_in[2];
  const int*   vlens   = (const int*)d_in[3];
  const float* Wq      = (const float*)d_in[4];
  const float* Wk      = (const float*)d_in[5];
  const float* wv      = (const float*)d_in[6];
  float* out = (float*)d_out;

  float* qh     = (float*)d_ws;                       // B*Q*H  = 2 MB (scaled)
  float* kh     = qh + (size_t)BDIM * QDIM * HDIM;    // B*K*H  = 2 MB (scaled)
  float* scores = kh + (size_t)BDIM * KDIM * HDIM;    // B*Q*K  = 32 MB

  proj_both<<<dim3(256), 256, 0, stream>>>(queries, keys, Wq, Wk, qh, kh);
  scores_kernel<<<dim3(KDIM / 64, QDIM / 32, BDIM), 256, 0, stream>>>(
      qh, kh, wv, vlens, scores);
  softmax_kernel<<<dim3(BDIM * QDIM / 4), 256, 0, stream>>>(scores, vlens);
  pv_kernel<<<dim3(QDIM / 16, BDIM), 256, 0, stream>>>(scores, values, vlens, out);
}

// Round 3
// 101.153 us; speedup vs baseline: 1.9532x; 1.4631x over previous
//
#include <hip/hip_runtime.h>

// Problem sizes (fixed by the reference)
#define BDIM 8
#define QDIM 1024
#define KDIM 1024
#define HDIM 64   // = DQ = DK = DV

constexpr float kLog2e = 1.4426950408889634f;
constexpr float kC2 = 2.0f * kLog2e;  // folded into projections: q' = c*q_hat

// sigma2(v) = 1/(1+2^v); tanh(x) = 1 - 2*sigma2(2*log2e*x). Infinities are
// exact: v->+inf -> 0 -> tanh=1; v->-inf -> 1 -> tanh=-1. No clamp needed.
__device__ __forceinline__ float sig2(float v) {
  return __builtin_amdgcn_rcpf(__builtin_amdgcn_exp2f(v) + 1.0f);
}

// ---------------------------------------------------------------------------
// K1: both projections in one launch; output pre-scaled by kC2.
// ---------------------------------------------------------------------------
__global__ __launch_bounds__(256) void proj_both(
    const float* __restrict__ queries, const float* __restrict__ keys,
    const float* __restrict__ Wq, const float* __restrict__ Wk,
    float* __restrict__ qh, float* __restrict__ kh) {
  const int bid = blockIdx.x;
  const bool isK = bid >= 128;
  const float* X = isK ? keys : queries;
  const float* W = isK ? Wk : Wq;
  float* Y = isK ? kh : qh;
  const long long base = (long long)(bid & 127) * 64 * 64;

  __shared__ __align__(16) float xs[64][68];
  __shared__ __align__(16) float ws[64][64];
  const int t = threadIdx.x;
  {
    const int r = t >> 4, sl = t & 15;
#pragma unroll
    for (int i = 0; i < 4; ++i) {
      *(float4*)&xs[r + i * 16][sl * 4] =
          *(const float4*)&X[base + (long long)(r + i * 16) * 64 + sl * 4];
      *(float4*)&ws[r + i * 16][sl * 4] =
          *(const float4*)&W[(r + i * 16) * 64 + sl * 4];
    }
  }
  __syncthreads();

  const int r = t >> 2;
  const int c0 = (t & 3) * 16;
  float acc[16];
#pragma unroll
  for (int j = 0; j < 16; ++j) acc[j] = 0.0f;

#pragma unroll 8
  for (int d = 0; d < 64; ++d) {
    const float xv = xs[r][d];
#pragma unroll
    for (int j4 = 0; j4 < 4; ++j4) {
      float4 w4 = *(float4*)&ws[d][c0 + j4 * 4];
      acc[j4 * 4 + 0] = fmaf(xv, w4.x, acc[j4 * 4 + 0]);
      acc[j4 * 4 + 1] = fmaf(xv, w4.y, acc[j4 * 4 + 1]);
      acc[j4 * 4 + 2] = fmaf(xv, w4.z, acc[j4 * 4 + 2]);
      acc[j4 * 4 + 3] = fmaf(xv, w4.w, acc[j4 * 4 + 3]);
    }
  }
#pragma unroll
  for (int j4 = 0; j4 < 4; ++j4) {
    float4 o = make_float4(acc[j4 * 4 + 0] * kC2, acc[j4 * 4 + 1] * kC2,
                           acc[j4 * 4 + 2] * kC2, acc[j4 * 4 + 3] * kC2);
    *(float4*)&Y[base + (long long)r * 64 + c0 + j4 * 4] = o;
  }
}

// ---------------------------------------------------------------------------
// K2: scores[b,q,k] = sumw - 2*sum_h wv[h]*sig2(q'+k')
// Compacted worklist: block g maps to the g-th VALID tile (b-major, k-tile
// major, q-tile fastest). Tile = 32q x 64k, 512 threads, thread owns 1q x 4k.
// Register double-buffered h-pipeline: stage h+1's 5 LDS b128 reads issue
// while stage h's 16 tanh-chains compute (~350 cyc) -> LDS latency hidden.
// Swizzle key=(k^(k>>2))&15: readers (lanes kg=0..15, k=4kg+j) hit 16
// distinct slots, 2-way banks (free); writers conflict-free.
// ---------------------------------------------------------------------------
__global__ __launch_bounds__(512, 6) void scores_kernel(
    const float* __restrict__ qh, const float* __restrict__ kh,
    const float* __restrict__ wv, const int* __restrict__ vlens,
    float* __restrict__ scores) {
  // ---- uniform worklist mapping (scalar) ----
  int pre[9];
  pre[0] = 0;
#pragma unroll
  for (int bb = 0; bb < 8; ++bb) {
    int nt = (vlens[bb] + 63) >> 6;
    nt = nt < 16 ? nt : 16;
    pre[bb + 1] = pre[bb] + (nt << 5);  // nt k-tiles x 32 q-tiles
  }
  const int g = blockIdx.x;
  if (g >= pre[8]) return;
  int b = 0;
#pragma unroll
  for (int i = 0; i < 7; ++i) b += (g >= pre[i + 1]);
  const int local = g - pre[b];
  const int q0 = (local & 31) * 32;  // q-tile fastest (division-free)
  const int k0 = (local >> 5) * 64;

  __shared__ __align__(16) float qs[32][68];
  __shared__ __align__(16) float ks[64][64];
  const int t = threadIdx.x;

  float sumw = 0.0f;
#pragma unroll
  for (int h = 0; h < 64; ++h) sumw += wv[h];  // uniform -> scalar loads

  {
    const int r = t >> 4, sl = t & 15;
    *(float4*)&qs[r][sl * 4] =
        *(const float4*)&qh[(long long)(b * QDIM + q0 + r) * 64 + sl * 4];
  }
#pragma unroll
  for (int i = 0; i < 2; ++i) {
    const int f = i * 512 + t;
    const int k = f >> 4, sl = f & 15;
    const int key = (k ^ (k >> 2)) & 15;
    *(float4*)&ks[k][(sl ^ key) * 4] =
        *(const float4*)&kh[(long long)(b * KDIM + k0 + k) * 64 + sl * 4];
  }
  __syncthreads();

  const int tq = t >> 4;            // 0..31: q row
  const int kg = t & 15;            // k group
  const int kbs = kg << 2;          // k base = 4*kg
  const int key0 = ((kbs + 0) ^ kg) & 15;
  const int key1 = ((kbs + 1) ^ kg) & 15;
  const int key2 = ((kbs + 2) ^ kg) & 15;
  const int key3 = ((kbs + 3) ^ kg) & 15;

  float acc0 = 0.0f, acc1 = 0.0f, acc2 = 0.0f, acc3 = 0.0f;

  float4 qA, kA0, kA1, kA2, kA3;
  float4 qB, kB0, kB1, kB2, kB3;

#define LOAD_STAGE(QF, K0, K1, K2, K3, H)                  \
  QF = *(const float4*)&qs[tq][(H) * 4];                   \
  K0 = *(const float4*)&ks[kbs + 0][((H) ^ key0) * 4];     \
  K1 = *(const float4*)&ks[kbs + 1][((H) ^ key1) * 4];     \
  K2 = *(const float4*)&ks[kbs + 2][((H) ^ key2) * 4];     \
  K3 = *(const float4*)&ks[kbs + 3][((H) ^ key3) * 4];

#define COMP_STAGE(QF, K0, K1, K2, K3, H)                  \
  {                                                        \
    const float w0 = wv[(H) * 4 + 0];                      \
    const float w1 = wv[(H) * 4 + 1];                      \
    const float w2 = wv[(H) * 4 + 2];                      \
    const float w3 = wv[(H) * 4 + 3];                      \
    acc0 = fmaf(w0, sig2(QF.x + K0.x), acc0);              \
    acc1 = fmaf(w0, sig2(QF.x + K1.x), acc1);              \
    acc2 = fmaf(w0, sig2(QF.x + K2.x), acc2);              \
    acc3 = fmaf(w0, sig2(QF.x + K3.x), acc3);              \
    acc0 = fmaf(w1, sig2(QF.y + K0.y), acc0);              \
    acc1 = fmaf(w1, sig2(QF.y + K1.y), acc1);              \
    acc2 = fmaf(w1, sig2(QF.y + K2.y), acc2);              \
    acc3 = fmaf(w1, sig2(QF.y + K3.y), acc3);              \
    acc0 = fmaf(w2, sig2(QF.z + K0.z), acc0);              \
    acc1 = fmaf(w2, sig2(QF.z + K1.z), acc1);              \
    acc2 = fmaf(w2, sig2(QF.z + K2.z), acc2);              \
    acc3 = fmaf(w2, sig2(QF.z + K3.z), acc3);              \
    acc0 = fmaf(w3, sig2(QF.w + K0.w), acc0);              \
    acc1 = fmaf(w3, sig2(QF.w + K1.w), acc1);              \
    acc2 = fmaf(w3, sig2(QF.w + K2.w), acc2);              \
    acc3 = fmaf(w3, sig2(QF.w + K3.w), acc3);              \
  }

  LOAD_STAGE(qA, kA0, kA1, kA2, kA3, 0)
#pragma unroll
  for (int h = 0; h < 16; h += 2) {
    LOAD_STAGE(qB, kB0, kB1, kB2, kB3, h + 1)
    COMP_STAGE(qA, kA0, kA1, kA2, kA3, h)
    if (h + 2 < 16) LOAD_STAGE(qA, kA0, kA1, kA2, kA3, h + 2)
    COMP_STAGE(qB, kB0, kB1, kB2, kB3, h + 1)
  }
#undef LOAD_STAGE
#undef COMP_STAGE

  float4 o = make_float4(fmaf(-2.0f, acc0, sumw), fmaf(-2.0f, acc1, sumw),
                         fmaf(-2.0f, acc2, sumw), fmaf(-2.0f, acc3, sumw));
  *(float4*)&scores[(long long)(b * QDIM + q0 + tq) * KDIM + k0 + kbs] = o;
}

// ---------------------------------------------------------------------------
// K3: masked row softmax, in place. block = 256 threads = 4 rows x 64 lanes.
// ---------------------------------------------------------------------------
__global__ __launch_bounds__(256) void softmax_kernel(
    float* __restrict__ scores, const int* __restrict__ vlens) {
  const int t = threadIdx.x;
  const int row = blockIdx.x * 4 + (t >> 6);
  const int b = row >> 10;  // QDIM = 1024
  const int lane = t & 63;
  const int vlen = vlens[b];
  float* srow = scores + (long long)row * KDIM;

  float4 v[4];
  float m = -3.0e38f;
#pragma unroll
  for (int i = 0; i < 4; ++i) {
    const int k = i * 256 + lane * 4;
    v[i] = *(const float4*)&srow[k];
    v[i].x = (k + 0 < vlen) ? v[i].x : -3.0e38f;
    v[i].y = (k + 1 < vlen) ? v[i].y : -3.0e38f;
    v[i].z = (k + 2 < vlen) ? v[i].z : -3.0e38f;
    v[i].w = (k + 3 < vlen) ? v[i].w : -3.0e38f;
    m = fmaxf(m, fmaxf(fmaxf(v[i].x, v[i].y), fmaxf(v[i].z, v[i].w)));
  }
#pragma unroll
  for (int s = 1; s < 64; s <<= 1) m = fmaxf(m, __shfl_xor(m, s, 64));

  float4 e[4];
  float sum = 0.0f;
#pragma unroll
  for (int i = 0; i < 4; ++i) {
    e[i].x = __builtin_amdgcn_exp2f((v[i].x - m) * kLog2e);
    e[i].y = __builtin_amdgcn_exp2f((v[i].y - m) * kLog2e);
    e[i].z = __builtin_amdgcn_exp2f((v[i].z - m) * kLog2e);
    e[i].w = __builtin_amdgcn_exp2f((v[i].w - m) * kLog2e);
    sum += (e[i].x + e[i].y) + (e[i].z + e[i].w);
  }
#pragma unroll
  for (int s = 1; s < 64; s <<= 1) sum += __shfl_xor(sum, s, 64);
  const float inv = __builtin_amdgcn_rcpf(sum);

#pragma unroll
  for (int i = 0; i < 4; ++i) {
    const int k = i * 256 + lane * 4;
    float4 o = make_float4(e[i].x * inv, e[i].y * inv, e[i].z * inv, e[i].w * inv);
    *(float4*)&srow[k] = o;
  }
}

// ---------------------------------------------------------------------------
// K4: out[b,q,d] = sum_k attn[b,q,k]*V[b,k,d]. 16 q-rows per block, k tiled
// by 64. Thread owns 1 q-row x 4 d. Only valid k-tiles contribute.
// ---------------------------------------------------------------------------
__global__ __launch_bounds__(256) void pv_kernel(
    const float* __restrict__ attn, const float* __restrict__ V,
    const int* __restrict__ vlens, float* __restrict__ out) {
  const int b = blockIdx.y;
  const int q0 = blockIdx.x * 16;
  const int vlen = vlens[b];
  const int ntiles = (vlen + 63) >> 6;

  __shared__ __align__(16) float as[16][68];
  __shared__ __align__(16) float vs[64][64];
  const int t = threadIdx.x;
  const int qp = t >> 4;
  const int dsl = (t & 15) * 4;

  float4 a0 = make_float4(0, 0, 0, 0);

  for (int kt = 0; kt < ntiles; ++kt) {
    __syncthreads();
    {
      const int r = t >> 4, sl = t & 15;
      *(float4*)&as[r][sl * 4] =
          *(const float4*)&attn[(long long)(b * QDIM + q0 + r) * KDIM + kt * 64 + sl * 4];
    }
#pragma unroll
    for (int i = 0; i < 4; ++i) {
      const int f = i * 256 + t;
      const int k = f >> 4, sl = f & 15;
      *(float4*)&vs[k][sl * 4] =
          *(const float4*)&V[(long long)(b * KDIM + kt * 64 + k) * 64 + sl * 4];
    }
    __syncthreads();

#pragma unroll 4
    for (int k4 = 0; k4 < 16; ++k4) {
      const float4 a4 = *(float4*)&as[qp][k4 * 4];
      const float aw[4] = {a4.x, a4.y, a4.z, a4.w};
#pragma unroll
      for (int e = 0; e < 4; ++e) {
        const float4 vv = *(float4*)&vs[k4 * 4 + e][dsl];
        a0.x = fmaf(aw[e], vv.x, a0.x);
        a0.y = fmaf(aw[e], vv.y, a0.y);
        a0.z = fmaf(aw[e], vv.z, a0.z);
        a0.w = fmaf(aw[e], vv.w, a0.w);
      }
    }
  }
  *(float4*)&out[(long long)(b * QDIM + q0 + qp) * 64 + dsl] = a0;
}

// ---------------------------------------------------------------------------
extern "C" void kernel_launch(void* const* d_in, const int* in_sizes, int n_in,
                              void* d_out, int out_size, void* d_ws, size_t ws_size,
                              hipStream_t stream) {
  const float* queries = (const float*)d_in[0];
  const float* keys    = (const float*)d_in[1];
  const float* values  = (const float*)d_in[2];
  const int*   vlens   = (const int*)d_in[3];
  const float* Wq      = (const float*)d_in[4];
  const float* Wk      = (const float*)d_in[5];
  const float* wv      = (const float*)d_in[6];
  float* out = (float*)d_out;

  float* qh     = (float*)d_ws;                       // B*Q*H  = 2 MB (scaled)
  float* kh     = qh + (size_t)BDIM * QDIM * HDIM;    // B*K*H  = 2 MB (scaled)
  float* scores = kh + (size_t)BDIM * KDIM * HDIM;    // B*Q*K  = 32 MB

  proj_both<<<dim3(256), 256, 0, stream>>>(queries, keys, Wq, Wk, qh, kh);
  // max tiles = 8 b * 32 q-tiles * 16 k-tiles = 4096; blocks past the
  // worklist end exit immediately (they are all at the dispatch tail).
  scores_kernel<<<dim3(4096), 512, 0, stream>>>(qh, kh, wv, vlens, scores);
  softmax_kernel<<<dim3(BDIM * QDIM / 4), 256, 0, stream>>>(scores, vlens);
  pv_kernel<<<dim3(QDIM / 16, BDIM), 256, 0, stream>>>(scores, values, vlens, out);
}